// Round 2
// baseline (1325.408 us; speedup 1.0000x reference)
//
#include <hip/hip_runtime.h>
#include <hip/hip_bf16.h>
#include <cstddef>

// Problem constants (GINConvFFT): B=32, N=512, L=12, H=64 -> D=768, S=2,
// ORDER=2 -> K=4 hops, M=256, OUT=64, rows R = B*N = 16384.
// Dtypes (round-1 finding): ALL inputs fp32, output fp32.
// Hop intermediates stored bf16 in ws (precision ok: 2% threshold).
#define B_   32
#define N_   512
#define D_   768
#define L_   12
#define H_   64
#define OUT_ 64
#define R_   (B_ * N_)

typedef __hip_bfloat16 bf16;

__device__ __forceinline__ float ldf(const float* p) { return *p; }
__device__ __forceinline__ float ldf(const bf16* p)  { return __bfloat162float(*p); }

// ---------------------------------------------------------------------------
// Kernel 1: diffusion hop.  O[b,n,d] = (1+eps)*X[b,n,d] + sum_m A[n,m]*X[b,m,d]
// A: [N,N] fp32, X: [B,N,D] (fp32 hop1 / bf16 hop2), O: [B,N,D] bf16.
// Tile 64x64 out, KT=32. grid (D/64, N/64, B), block 256.
// ---------------------------------------------------------------------------
#define KT 32
template <typename TX>
__global__ __launch_bounds__(256) void diffuse_gemm(
    const float* __restrict__ A, const TX* __restrict__ X,
    const float* __restrict__ epsp, bf16* __restrict__ O)
{
    const int b  = blockIdx.z;
    const int n0 = blockIdx.y * 64;
    const int d0 = blockIdx.x * 64;
    __shared__ float As[64][KT + 1];
    __shared__ float Xs[KT][64 + 1];
    const int tid = threadIdx.x;
    const int tx = tid & 15, ty = tid >> 4;   // 16x16 threads, 4x4 micro-tile
    float acc[4][4] = {};
    const TX* Xb = X + (size_t)b * N_ * D_;

    for (int m0 = 0; m0 < N_; m0 += KT) {
#pragma unroll
        for (int i = 0; i < 8; ++i) {          // A tile: 64 x 32
            int idx = tid + i * 256;
            int r = idx >> 5, c = idx & 31;
            As[r][c] = A[(size_t)(n0 + r) * N_ + m0 + c];
        }
#pragma unroll
        for (int i = 0; i < 8; ++i) {          // X tile: 32 x 64
            int idx = tid + i * 256;
            int r = idx >> 6, c = idx & 63;
            Xs[r][c] = ldf(&Xb[(size_t)(m0 + r) * D_ + d0 + c]);
        }
        __syncthreads();
#pragma unroll
        for (int kk = 0; kk < KT; ++kk) {
            float av[4], xv[4];
#pragma unroll
            for (int i = 0; i < 4; ++i) av[i] = As[ty * 4 + i][kk];
#pragma unroll
            for (int j = 0; j < 4; ++j) xv[j] = Xs[kk][tx * 4 + j];
#pragma unroll
            for (int i = 0; i < 4; ++i)
#pragma unroll
                for (int j = 0; j < 4; ++j) acc[i][j] += av[i] * xv[j];
        }
        __syncthreads();
    }

    const float f = 1.0f + epsp[0];
#pragma unroll
    for (int i = 0; i < 4; ++i) {
        int n = n0 + ty * 4 + i;
#pragma unroll
        for (int j = 0; j < 4; ++j) {
            int d = d0 + tx * 4 + j;
            size_t off = (size_t)n * D_ + d;
            float v = f * ldf(&Xb[off]) + acc[i][j];
            O[(size_t)b * N_ * D_ + off] = __float2bfloat16(v);
        }
    }
}

// ---------------------------------------------------------------------------
// Kernel 2: projection for one hop k.
// Y1[r,o] (+)= sum_d H[r,d] * weight[l, h*4+k, o], d = l*64+h.
// H: [R,768] bf16, weight: [12,256,64] fp32, Y1: [R,64] fp32.
// grid R/64, block 256. kidx==0 initializes Y1 (ws is poisoned).
// ---------------------------------------------------------------------------
__global__ __launch_bounds__(256) void proj_gemm(
    const bf16* __restrict__ Hp, const float* __restrict__ W,
    float* __restrict__ Y1, int kidx)
{
    const int r0 = blockIdx.x * 64;
    __shared__ float Hs[64][KT + 1];
    __shared__ float Ws[KT][64 + 1];
    const int tid = threadIdx.x;
    const int tx = tid & 15, ty = tid >> 4;
    float acc[4][4] = {};

    for (int dd0 = 0; dd0 < D_; dd0 += KT) {
#pragma unroll
        for (int i = 0; i < 8; ++i) {          // H tile: 64 rows x 32 d
            int idx = tid + i * 256;
            int r = idx >> 5, c = idx & 31;
            Hs[r][c] = ldf(&Hp[(size_t)(r0 + r) * D_ + dd0 + c]);
        }
#pragma unroll
        for (int i = 0; i < 8; ++i) {          // W tile: 32 d x 64 o
            int idx = tid + i * 256;
            int rr = idx >> 6, c = idx & 63;
            int d = dd0 + rr;
            int l = d >> 6, h = d & 63;
            Ws[rr][c] = W[((size_t)l * 256 + h * 4 + kidx) * 64 + c];
        }
        __syncthreads();
#pragma unroll
        for (int kk = 0; kk < KT; ++kk) {
            float av[4], wv[4];
#pragma unroll
            for (int i = 0; i < 4; ++i) av[i] = Hs[ty * 4 + i][kk];
#pragma unroll
            for (int j = 0; j < 4; ++j) wv[j] = Ws[kk][tx * 4 + j];
#pragma unroll
            for (int i = 0; i < 4; ++i)
#pragma unroll
                for (int j = 0; j < 4; ++j) acc[i][j] += av[i] * wv[j];
        }
        __syncthreads();
    }

#pragma unroll
    for (int i = 0; i < 4; ++i) {
        int r = r0 + ty * 4 + i;
#pragma unroll
        for (int j = 0; j < 4; ++j) {
            int o = tx * 4 + j;
            size_t off = (size_t)r * OUT_ + o;
            float base = (kidx == 0) ? 0.0f : Y1[off];
            Y1[off] = base + acc[i][j];
        }
    }
}

// ---------------------------------------------------------------------------
// Kernel 3a: per-block partial sums for BN. grid 256, each block = 64 rows.
// part[b][0][c]=sum, part[b][1][c]=sumsq  (layout b*128 + {0,64} + c)
// ---------------------------------------------------------------------------
__global__ __launch_bounds__(256) void bn_partial(
    const float* __restrict__ Y1, float* __restrict__ part)
{
    const int blk = blockIdx.x, tid = threadIdx.x;
    const int c = tid & 63, g = tid >> 6;     // 4 row-groups
    float s = 0.f, s2 = 0.f;
    for (int r = blk * 64 + g; r < blk * 64 + 64; r += 4) {
        float v = Y1[(size_t)r * OUT_ + c];
        s += v; s2 += v * v;
    }
    __shared__ float ls[4][64], ls2[4][64];
    ls[g][c] = s; ls2[g][c] = s2;
    __syncthreads();
    if (tid < 64) {
        float t = 0.f, t2 = 0.f;
#pragma unroll
        for (int g2 = 0; g2 < 4; ++g2) { t += ls[g2][tid]; t2 += ls2[g2][tid]; }
        part[blk * 128 + tid]      = t;
        part[blk * 128 + 64 + tid] = t2;
    }
}

// Kernel 3b: final stats. stats[c]=mean, stats[64+c]=rsqrt(var+eps). 1 block.
__global__ __launch_bounds__(256) void bn_final(
    const float* __restrict__ part, float* __restrict__ stats)
{
    const int tid = threadIdx.x;
    const int c = tid & 63, g = tid >> 6;
    float s = 0.f, s2 = 0.f;
    for (int b = g; b < 256; b += 4) {
        s  += part[b * 128 + c];
        s2 += part[b * 128 + 64 + c];
    }
    __shared__ float ls[4][64], ls2[4][64];
    ls[g][c] = s; ls2[g][c] = s2;
    __syncthreads();
    if (tid < 64) {
        float t = 0.f, t2 = 0.f;
#pragma unroll
        for (int g2 = 0; g2 < 4; ++g2) { t += ls[g2][tid]; t2 += ls2[g2][tid]; }
        float mean = t * (1.0f / R_);
        float var  = t2 * (1.0f / R_) - mean * mean;
        stats[tid]      = mean;
        stats[64 + tid] = rsqrtf(var + 1e-5f);
    }
}

// ---------------------------------------------------------------------------
// Kernel 4: normalize + relu + (y @ w2^T) + b2 -> fp32 out.
// out[r,o] = sum_c relu((Y1[r,c]-mean[c])*rstd[c]*gamma[c]+beta[c]) * w2[o,c] + b2[o]
// grid R/4, block 256 (4 rows x 64 channels).
// ---------------------------------------------------------------------------
__global__ __launch_bounds__(256) void bn_relu_out(
    const float* __restrict__ Y1, const float* __restrict__ stats,
    const float* __restrict__ gamma, const float* __restrict__ beta,
    const float* __restrict__ w2, const float* __restrict__ b2,
    float* __restrict__ out)
{
    __shared__ float w2s[64][65];
    __shared__ float ga[64], be[64], mn[64], rs[64], bb[64];
    __shared__ float yrow[4][65];
    const int tid = threadIdx.x;
#pragma unroll
    for (int i = 0; i < 16; ++i) {
        int idx = tid + i * 256;
        w2s[idx >> 6][idx & 63] = w2[idx];
    }
    if (tid < 64) {
        ga[tid] = gamma[tid]; be[tid] = beta[tid];
        mn[tid] = stats[tid]; rs[tid] = stats[64 + tid];
        bb[tid] = b2[tid];
    }
    __syncthreads();
    const int rl = tid >> 6, o = tid & 63;
    const int r = blockIdx.x * 4 + rl;
    float v = Y1[(size_t)r * OUT_ + o];
    v = (v - mn[o]) * rs[o] * ga[o] + be[o];
    yrow[rl][o] = fmaxf(v, 0.f);
    __syncthreads();
    float acc = bb[o];
#pragma unroll
    for (int c = 0; c < 64; ++c) acc += yrow[rl][c] * w2s[o][c];
    out[(size_t)r * OUT_ + o] = acc;
}

// ---------------------------------------------------------------------------
extern "C" void kernel_launch(void* const* d_in, const int* in_sizes, int n_in,
                              void* d_out, int out_size, void* d_ws, size_t ws_size,
                              hipStream_t stream)
{
    const float* x       = (const float*)d_in[0];   // [B,N,L,H] = [B,N,768]
    const float* support = (const float*)d_in[1];   // [2,N,N]
    const float* weight  = (const float*)d_in[2];   // [12,256,64]
    const float* eps     = (const float*)d_in[3];   // [1]
    const float* gamma   = (const float*)d_in[4];   // [64]
    const float* beta    = (const float*)d_in[5];   // [64]
    const float* w2      = (const float*)d_in[6];   // [64,64]
    const float* b2      = (const float*)d_in[7];   // [64]
    float* out = (float*)d_out;                     // [B,N,64]

    char* ws = (char*)d_ws;
    const size_t hop_bytes = (size_t)B_ * N_ * D_ * sizeof(bf16); // 25,165,824
    bf16*  buf0  = (bf16*)(ws);                       // h1 (reused s0 then s1)
    bf16*  buf1  = (bf16*)(ws + hop_bytes);           // h2
    float* Y1    = (float*)(ws + 2 * hop_bytes);      // [R,64] fp32
    float* part  = (float*)(ws + 2 * hop_bytes + (size_t)R_ * OUT_ * 4);
    float* stats = part + 256 * 128;

    dim3 gD(D_ / 64, N_ / 64, B_), b256(256);
    const float* A0 = support;
    const float* A1 = support + (size_t)N_ * N_;

    // support 0
    diffuse_gemm<float><<<gD, b256, 0, stream>>>(A0, x,    eps, buf0);   // s0 hop1
    proj_gemm  <<<R_ / 64, b256, 0, stream>>>(buf0, weight, Y1, 0);
    diffuse_gemm<bf16> <<<gD, b256, 0, stream>>>(A0, buf0, eps, buf1);   // s0 hop2
    proj_gemm  <<<R_ / 64, b256, 0, stream>>>(buf1, weight, Y1, 1);
    // support 1 (reuse buffers)
    diffuse_gemm<float><<<gD, b256, 0, stream>>>(A1, x,    eps, buf0);   // s1 hop1
    proj_gemm  <<<R_ / 64, b256, 0, stream>>>(buf0, weight, Y1, 2);
    diffuse_gemm<bf16> <<<gD, b256, 0, stream>>>(A1, buf0, eps, buf1);   // s1 hop2
    proj_gemm  <<<R_ / 64, b256, 0, stream>>>(buf1, weight, Y1, 3);

    bn_partial <<<256, b256, 0, stream>>>(Y1, part);
    bn_final   <<<1,   b256, 0, stream>>>(part, stats);
    bn_relu_out<<<R_ / 4, b256, 0, stream>>>(Y1, stats, gamma, beta, w2, b2, out);
}

// Round 3
// 335.392 us; speedup vs baseline: 3.9518x; 3.9518x over previous
//
#include <hip/hip_runtime.h>
#include <hip/hip_bf16.h>
#include <cstddef>
#include <cstdint>

// GINConvFFT on MI355X, round 3: algebraic refactor + MFMA.
// hop1 = M x, hop2 = M^2 x, M = (1+eps)I + A_s  (per support s).
// Mall bf16 [4*512, 512] rows = [s0h1, s0h2, s1h1, s1h2] hop matrices.
// Diffusion: C[b][nh][d] = sum_m Mall[nh][m] * xT[b][d][m]   (P*Q^T, MFMA)
// Projection: Y1[k][o][r] = sum_d Wt[k][o][d] * H[b][n][d]   (P*Q^T, MFMA)
// Then BN stats + fused BN/ReLU/w2 epilogue.
#define B_   32
#define N_   512
#define D_   768
#define OUT_ 64
#define R_   (B_ * N_)

typedef unsigned short u16;
typedef __bf16 bf16x8 __attribute__((ext_vector_type(8)));
typedef float  f32x4  __attribute__((ext_vector_type(4)));
typedef unsigned short u16x8 __attribute__((ext_vector_type(8)));

__device__ __forceinline__ u16 f2bf(float f) {
    __hip_bfloat16 h = __float2bfloat16(f);
    return __builtin_bit_cast(u16, h);
}

__device__ __forceinline__ f32x4 mfma16(u16x8 a, u16x8 b, f32x4 c) {
    return __builtin_amdgcn_mfma_f32_16x16x32_bf16(
        __builtin_bit_cast(bf16x8, a), __builtin_bit_cast(bf16x8, b), c, 0, 0, 0);
}

// async global->LDS, 16B per lane; LDS dest = base + lane*16 (wave-uniform base)
__device__ __forceinline__ void gl2lds16(const void* g, void* l) {
    __builtin_amdgcn_global_load_lds(
        (const __attribute__((address_space(1))) unsigned int*)g,
        (__attribute__((address_space(3))) unsigned int*)l, 16, 0, 0);
}

// ---------------------------------------------------------------------------
// x [B][N][D] fp32 -> Xt0 [B][D][N] bf16 (transpose + convert)
// ---------------------------------------------------------------------------
__global__ __launch_bounds__(256) void convert_x(
    const float* __restrict__ x, u16* __restrict__ Xt)
{
    __shared__ float t[32][33];
    const int tid = threadIdx.x;
    const int d0 = blockIdx.x * 32, n0 = blockIdx.y * 32, b = blockIdx.z;
    const float* xb = x + (size_t)b * N_ * D_;
#pragma unroll
    for (int p = 0; p < 4; ++p) {
        int nl = p * 8 + (tid >> 5), dl = tid & 31;
        t[nl][dl] = xb[(size_t)(n0 + nl) * D_ + d0 + dl];
    }
    __syncthreads();
    u16* Xb = Xt + (size_t)b * D_ * N_;
#pragma unroll
    for (int p = 0; p < 4; ++p) {
        int dl = p * 8 + (tid >> 5), nl = tid & 31;
        Xb[(size_t)(d0 + dl) * N_ + n0 + nl] = f2bf(t[nl][dl]);
    }
}

// ---------------------------------------------------------------------------
// Ms[s] = support[s] + (1+eps)I (fp32), and Mall rows for hop1 of each s (bf16)
// grid (512, 2)
// ---------------------------------------------------------------------------
__global__ __launch_bounds__(256) void build_M(
    const float* __restrict__ support, const float* __restrict__ epsp,
    float* __restrict__ Ms, u16* __restrict__ Mall)
{
    const int n = blockIdx.x, s = blockIdx.y, tid = threadIdx.x;
    const float f = 1.0f + epsp[0];
#pragma unroll
    for (int p = 0; p < 2; ++p) {
        int m = p * 256 + tid;
        float v = support[(size_t)s * N_ * N_ + (size_t)n * N_ + m];
        if (m == n) v += f;
        Ms[(size_t)s * N_ * N_ + (size_t)n * N_ + m] = v;
        Mall[(size_t)s * 1024 * 512 + (size_t)n * 512 + m] = f2bf(v);
    }
}

// ---------------------------------------------------------------------------
// M^2 (fp32 vector GEMM, 512x512x512 per support) -> Mall hop2 rows (bf16)
// grid (8, 8, 2)
// ---------------------------------------------------------------------------
__global__ __launch_bounds__(256) void msq(
    const float* __restrict__ Ms, u16* __restrict__ Mall)
{
    const int s = blockIdx.z;
    const int n0 = blockIdx.y * 64, m0 = blockIdx.x * 64;
    const float* M = Ms + (size_t)s * N_ * N_;
    __shared__ float As[64][33];
    __shared__ float Bs[32][65];
    const int tid = threadIdx.x, tx = tid & 15, ty = tid >> 4;
    float acc[4][4] = {};
    for (int k0 = 0; k0 < 512; k0 += 32) {
#pragma unroll
        for (int i = 0; i < 8; ++i) {
            int idx = tid + i * 256;
            As[idx >> 5][idx & 31] = M[(size_t)(n0 + (idx >> 5)) * 512 + k0 + (idx & 31)];
        }
#pragma unroll
        for (int i = 0; i < 8; ++i) {
            int idx = tid + i * 256;
            Bs[idx >> 6][idx & 63] = M[(size_t)(k0 + (idx >> 6)) * 512 + m0 + (idx & 63)];
        }
        __syncthreads();
#pragma unroll
        for (int kk = 0; kk < 32; ++kk) {
            float av[4], bv[4];
#pragma unroll
            for (int i = 0; i < 4; ++i) av[i] = As[ty * 4 + i][kk];
#pragma unroll
            for (int j = 0; j < 4; ++j) bv[j] = Bs[kk][tx * 4 + j];
#pragma unroll
            for (int i = 0; i < 4; ++i)
#pragma unroll
                for (int j = 0; j < 4; ++j) acc[i][j] += av[i] * bv[j];
        }
        __syncthreads();
    }
#pragma unroll
    for (int i = 0; i < 4; ++i)
#pragma unroll
        for (int j = 0; j < 4; ++j)
            Mall[(size_t)s * 1024 * 512 + (size_t)512 * 512 +
                 (size_t)(n0 + ty * 4 + i) * 512 + m0 + tx * 4 + j] = f2bf(acc[i][j]);
}

// ---------------------------------------------------------------------------
// Wt[k][o][d] = weight[l][h*4+k][o], d = l*64+h  (bf16). grid 768.
// ---------------------------------------------------------------------------
__global__ __launch_bounds__(256) void build_Wt(
    const float* __restrict__ w, u16* __restrict__ Wt)
{
    int idx = blockIdx.x * 256 + threadIdx.x;      // 4*64*768 = 196608
    int k = idx / 49152, rem = idx % 49152;
    int o = rem / 768, d = rem % 768;
    int l = d >> 6, hh = d & 63;
    Wt[idx] = f2bf(w[((size_t)l * 256 + hh * 4 + k) * 64 + o]);
}

// ---------------------------------------------------------------------------
// Big MFMA GEMM: C[b][i][j] = sum_k P[i][k] * Q[b][j][k]
// P = Mall half [1024 x 512] bf16, Q = Xt0 [32][768][512], C = Hbuf [32][1024][768].
// 128x128 tile, BK=32, fragment-ordered LDS staging via global_load_lds.
// grid (6, 8, 32), block 256 (4 waves, 2x2 of 64x64).
// ---------------------------------------------------------------------------
__global__ __launch_bounds__(256) void gemm_big(
    const u16* __restrict__ P, const u16* __restrict__ Q, u16* __restrict__ C)
{
    __shared__ __align__(16) char smem[4 * 9216];   // 16KB staging / 36KB epilogue overlay
    u16* Ps = (u16*)smem;                           // 8 subtiles x 512 u16
    u16* Qs = (u16*)(smem + 8192);
    const int tid = threadIdx.x, lane = tid & 63, wid = tid >> 6;
    const int wr = wid >> 1, wc = wid & 1;
    const int i0 = blockIdx.y * 128, j0 = blockIdx.x * 128, b = blockIdx.z;
    const u16* Qb = Q + (size_t)b * D_ * N_;
    const int lrow = lane & 15, lk = (lane >> 4) * 8;

    const u16* gsrc[4]; u16* ldst[4];
#pragma unroll
    for (int t = 0; t < 4; ++t) {
        int idx = wid * 4 + t;
        if (idx < 8) {
            gsrc[t] = P + (size_t)(i0 + idx * 16 + lrow) * 512 + lk;
            ldst[t] = Ps + idx * 512;
        } else {
            int s2 = idx - 8;
            gsrc[t] = Qb + (size_t)(j0 + s2 * 16 + lrow) * 512 + lk;
            ldst[t] = Qs + s2 * 512;
        }
    }
    f32x4 acc[4][4] = {};
    for (int k0 = 0; k0 < 512; k0 += 32) {
#pragma unroll
        for (int t = 0; t < 4; ++t) gl2lds16(gsrc[t], ldst[t]);
#pragma unroll
        for (int t = 0; t < 4; ++t) gsrc[t] += 32;
        __syncthreads();
        u16x8 af[4], bq[4];
#pragma unroll
        for (int f = 0; f < 4; ++f)
            af[f] = *(const u16x8*)(Ps + (wr * 4 + f) * 512 + lane * 8);
#pragma unroll
        for (int f = 0; f < 4; ++f)
            bq[f] = *(const u16x8*)(Qs + (wc * 4 + f) * 512 + lane * 8);
#pragma unroll
        for (int fi = 0; fi < 4; ++fi)
#pragma unroll
            for (int fj = 0; fj < 4; ++fj)
                acc[fi][fj] = mfma16(af[fi], bq[fj], acc[fi][fj]);
        __syncthreads();
    }
    // epilogue: per-wave 64x64 repack via LDS (row stride 72 u16 = 144B, 16B-aligned)
    u16* Rw = (u16*)(smem + wid * 9216);
    const int q = lane >> 4;
#pragma unroll
    for (int fi = 0; fi < 4; ++fi)
#pragma unroll
        for (int fj = 0; fj < 4; ++fj)
#pragma unroll
            for (int r = 0; r < 4; ++r)
                Rw[(fi * 16 + q * 4 + r) * 72 + fj * 16 + lrow] = f2bf(acc[fi][fj][r]);
    __syncthreads();
    u16* Cb = C + (size_t)b * 1024 * D_;
#pragma unroll
    for (int p = 0; p < 8; ++p) {
        int row = p * 8 + (lane >> 3);
        int cc = (lane & 7) * 8;
        u16x8 v = *(const u16x8*)(Rw + row * 72 + cc);
        *(u16x8*)(Cb + (size_t)(i0 + wr * 64 + row) * D_ + j0 + wc * 64 + cc) = v;
    }
}

// ---------------------------------------------------------------------------
// Projection MFMA: Y1[(s*2+h)][o][b*512+n] = sum_d Wt[s*2+h][o][d] * H[b][h*512+n][d]
// tile 64(o) x 256(n), BK=32, K=768. grid (2, 2, 32), block 256 (4 waves 1x4).
// ---------------------------------------------------------------------------
__global__ __launch_bounds__(256) void proj_mfma(
    const u16* __restrict__ Wt, const u16* __restrict__ Hb,
    float* __restrict__ Y1, int s)
{
    __shared__ __align__(16) char smem[20480];
    u16* Ps = (u16*)smem;             // 4 subtiles (o rows)
    u16* Qs = (u16*)(smem + 4096);    // 16 subtiles (n rows)
    const int tid = threadIdx.x, lane = tid & 63, wid = tid >> 6;
    const int n0 = blockIdx.x * 256, h = blockIdx.y, b = blockIdx.z;
    const u16* Pg = Wt + (size_t)(s * 2 + h) * 64 * D_;
    const u16* Qg = Hb + (size_t)b * 1024 * D_ + (size_t)(h * 512 + n0) * D_;
    const int lrow = lane & 15, lk = (lane >> 4) * 8;

    const u16* gsrc[5]; u16* ldst[5];
    gsrc[0] = Pg + (size_t)(wid * 16 + lrow) * D_ + lk;
    ldst[0] = Ps + wid * 512;
#pragma unroll
    for (int t = 0; t < 4; ++t) {
        int s2 = wid * 4 + t;
        gsrc[t + 1] = Qg + (size_t)(s2 * 16 + lrow) * D_ + lk;
        ldst[t + 1] = Qs + s2 * 512;
    }
    f32x4 acc[4][4] = {};
    for (int k0 = 0; k0 < D_; k0 += 32) {
#pragma unroll
        for (int t = 0; t < 5; ++t) gl2lds16(gsrc[t], ldst[t]);
#pragma unroll
        for (int t = 0; t < 5; ++t) gsrc[t] += 32;
        __syncthreads();
        u16x8 af[4], bq[4];
#pragma unroll
        for (int f = 0; f < 4; ++f)
            af[f] = *(const u16x8*)(Ps + f * 512 + lane * 8);
#pragma unroll
        for (int f = 0; f < 4; ++f)
            bq[f] = *(const u16x8*)(Qs + (wid * 4 + f) * 512 + lane * 8);
#pragma unroll
        for (int fi = 0; fi < 4; ++fi)
#pragma unroll
            for (int fj = 0; fj < 4; ++fj)
                acc[fi][fj] = mfma16(af[fi], bq[fj], acc[fi][fj]);
        __syncthreads();
    }
    const int q = lane >> 4;
    float* Yk = Y1 + (size_t)(s * 2 + h) * 64 * R_;
#pragma unroll
    for (int fi = 0; fi < 4; ++fi)
#pragma unroll
        for (int fj = 0; fj < 4; ++fj)
#pragma unroll
            for (int r = 0; r < 4; ++r) {
                int o = fi * 16 + q * 4 + r;
                int rr = b * 512 + n0 + wid * 64 + fj * 16 + lrow;
                Yk[(size_t)o * R_ + rr] = acc[fi][fj][r];
            }
}

// ---------------------------------------------------------------------------
// BN stats over r per channel o, summing the 4 hop buffers. grid 64.
// stats[o]=mean, stats[64+o]=rsqrt(var+1e-5)
// ---------------------------------------------------------------------------
__global__ __launch_bounds__(256) void bn_stats(
    const float* __restrict__ Y1, float* __restrict__ stats)
{
    const int o = blockIdx.x, tid = threadIdx.x;
    float su = 0.f, s2 = 0.f;
    for (int i = tid; i < R_; i += 256) {
        float v = 0.f;
#pragma unroll
        for (int k = 0; k < 4; ++k) v += Y1[(size_t)(k * 64 + o) * R_ + i];
        su += v; s2 += v * v;
    }
    __shared__ float ss[256], ssq[256];
    ss[tid] = su; ssq[tid] = s2;
    __syncthreads();
    for (int st = 128; st > 0; st >>= 1) {
        if (tid < st) { ss[tid] += ss[tid + st]; ssq[tid] += ssq[tid + st]; }
        __syncthreads();
    }
    if (tid == 0) {
        float mean = ss[0] * (1.0f / R_);
        float var  = ssq[0] * (1.0f / R_) - mean * mean;
        stats[o] = mean;
        stats[64 + o] = rsqrtf(var + 1e-5f);
    }
}

// ---------------------------------------------------------------------------
// Fused BN + ReLU + w2 GEMM + b2. grid 256 (64 rows each), block 256.
// out[r][o] = sum_c relu(bn(Y[r][c])) * w2[o][c] + b2[o]
// ---------------------------------------------------------------------------
__global__ __launch_bounds__(256) void bn_out(
    const float* __restrict__ Y1, const float* __restrict__ stats,
    const float* __restrict__ gamma, const float* __restrict__ beta,
    const float* __restrict__ w2, const float* __restrict__ b2,
    float* __restrict__ out)
{
    __shared__ float ys[64 * 68];    // stride 68 floats (16B aligned rows)
    __shared__ float w2s[64 * 65];   // stride 65 (odd -> conflict-free col reads)
    __shared__ float mn[64], rs[64], ga[64], be[64], bb[64];
    const int tid = threadIdx.x;
    const int r0 = blockIdx.x * 64;
#pragma unroll
    for (int i = 0; i < 16; ++i) {
        int idx = tid + i * 256;
        w2s[(idx >> 6) * 65 + (idx & 63)] = w2[idx];
    }
    if (tid < 64) {
        mn[tid] = stats[tid]; rs[tid] = stats[64 + tid];
        ga[tid] = gamma[tid]; be[tid] = beta[tid]; bb[tid] = b2[tid];
    }
    __syncthreads();
#pragma unroll
    for (int p = 0; p < 16; ++p) {
        int c = p * 4 + (tid >> 6), rl = tid & 63;
        float v = 0.f;
#pragma unroll
        for (int k = 0; k < 4; ++k) v += Y1[(size_t)(k * 64 + c) * R_ + r0 + rl];
        v = (v - mn[c]) * rs[c] * ga[c] + be[c];
        ys[c * 68 + rl] = fmaxf(v, 0.f);
    }
    __syncthreads();
    const int ol = tid & 63, rg = tid >> 6;   // rg uniform per wave
    float acc[16];
#pragma unroll
    for (int j = 0; j < 16; ++j) acc[j] = bb[ol];
    for (int c = 0; c < 64; ++c) {
        float wv = w2s[ol * 65 + c];
        const float* yr = ys + c * 68 + rg * 16;
        f32x4 y0 = *(const f32x4*)(yr);
        f32x4 y1 = *(const f32x4*)(yr + 4);
        f32x4 y2 = *(const f32x4*)(yr + 8);
        f32x4 y3 = *(const f32x4*)(yr + 12);
#pragma unroll
        for (int j = 0; j < 4; ++j) {
            acc[j]      = fmaf(wv, y0[j], acc[j]);
            acc[4 + j]  = fmaf(wv, y1[j], acc[4 + j]);
            acc[8 + j]  = fmaf(wv, y2[j], acc[8 + j]);
            acc[12 + j] = fmaf(wv, y3[j], acc[12 + j]);
        }
    }
#pragma unroll
    for (int j = 0; j < 16; ++j)
        out[(size_t)(r0 + rg * 16 + j) * OUT_ + ol] = acc[j];
}

// ---------------------------------------------------------------------------
extern "C" void kernel_launch(void* const* d_in, const int* in_sizes, int n_in,
                              void* d_out, int out_size, void* d_ws, size_t ws_size,
                              hipStream_t stream)
{
    const float* x       = (const float*)d_in[0];
    const float* support = (const float*)d_in[1];
    const float* weight  = (const float*)d_in[2];
    const float* eps     = (const float*)d_in[3];
    const float* gamma   = (const float*)d_in[4];
    const float* beta    = (const float*)d_in[5];
    const float* w2      = (const float*)d_in[6];
    const float* b2      = (const float*)d_in[7];
    float* out = (float*)d_out;

    char* ws = (char*)d_ws;
    u16*   Xt0   = (u16*)(ws);                      // 25,165,824 B
    u16*   Mall  = (u16*)(ws + 25165824);           //  2,097,152
    float* Ms    = (float*)(ws + 27262976);         //  2,097,152
    u16*   Wt    = (u16*)(ws + 29360128);           //    393,216
    u16*   Hbuf  = (u16*)(ws + 29753344);           // 50,331,648
    float* Y1    = (float*)(ws + 80084992);         // 16,777,216 (4 hop bufs)
    float* stats = (float*)(ws + 96862208);         //        512

    convert_x<<<dim3(24, 16, 32), 256, 0, stream>>>(x, Xt0);
    build_M  <<<dim3(512, 2),     256, 0, stream>>>(support, eps, Ms, Mall);
    msq      <<<dim3(8, 8, 2),    256, 0, stream>>>(Ms, Mall);
    build_Wt <<<768,              256, 0, stream>>>(weight, Wt);
    for (int s = 0; s < 2; ++s) {
        gemm_big <<<dim3(6, 8, 32), 256, 0, stream>>>(Mall + (size_t)s * 1024 * 512, Xt0, Hbuf);
        proj_mfma<<<dim3(2, 2, 32), 256, 0, stream>>>(Wt, Hbuf, Y1, s);
    }
    bn_stats<<<64,  256, 0, stream>>>(Y1, stats);
    bn_out  <<<256, 256, 0, stream>>>(Y1, stats, gamma, beta, w2, b2, out);
}

// Round 4
// 192.107 us; speedup vs baseline: 6.8993x; 1.7459x over previous
//
#include <hip/hip_runtime.h>
#include <hip/hip_bf16.h>
#include <cstddef>
#include <cstdint>

// GINConvFFT round 4: project-then-diffuse reordering.
//   Z[k][b][o][m] = sum_d Wt[k][o][d] * x[b][m][d]        (12.9 GF, MFMA)
//   Y[k][b][n][o] = sum_m Mall[k][n][m] * Z[k][b][o][m]   (8.6 GF, MFMA)
//   Mall[2s]=M_s=(1+eps)I+A_s, Mall[2s+1]=M_s^2 (MFMA from M,MT bf16)
// Then BN stats + fused BN/ReLU/w2 epilogue. All accumulation fp32.
#define B_   32
#define N_   512
#define D_   768
#define OUT_ 64
#define R_   (B_ * N_)

typedef unsigned short u16;
typedef __bf16 bf16x8 __attribute__((ext_vector_type(8)));
typedef float  f32x4  __attribute__((ext_vector_type(4)));
typedef unsigned short u16x8 __attribute__((ext_vector_type(8)));

__device__ __forceinline__ u16 f2bf(float f) {
    __hip_bfloat16 h = __float2bfloat16(f);
    return __builtin_bit_cast(u16, h);
}

__device__ __forceinline__ f32x4 mfma16(u16x8 a, u16x8 b, f32x4 c) {
    return __builtin_amdgcn_mfma_f32_16x16x32_bf16(
        __builtin_bit_cast(bf16x8, a), __builtin_bit_cast(bf16x8, b), c, 0, 0, 0);
}

// async global->LDS, 16B/lane; LDS dest = wave-uniform base + lane*16
__device__ __forceinline__ void gl2lds16(const void* g, void* l) {
    __builtin_amdgcn_global_load_lds(
        (const __attribute__((address_space(1))) unsigned int*)g,
        (__attribute__((address_space(3))) unsigned int*)l, 16, 0, 0);
}

// ---------------------------------------------------------------------------
// x fp32 [R][768] -> xb bf16 [R][768] (cast only; rows already d-contig)
// ---------------------------------------------------------------------------
__global__ __launch_bounds__(256) void cast_x(
    const float* __restrict__ x, u16* __restrict__ xb)
{
    int i = (blockIdx.x * 256 + threadIdx.x) * 8;
    f32x4 a = *(const f32x4*)(x + i);
    f32x4 b = *(const f32x4*)(x + i + 4);
    u16x8 o;
#pragma unroll
    for (int j = 0; j < 4; ++j) { o[j] = f2bf(a[j]); o[4 + j] = f2bf(b[j]); }
    *(u16x8*)(xb + i) = o;
}

// ---------------------------------------------------------------------------
// M = (1+eps)I + A_s -> Mall[2s] rows (bf16) and MT[s] (transpose, bf16)
// grid (16,16,2), 32x32 tiles
// ---------------------------------------------------------------------------
__global__ __launch_bounds__(256) void build_M(
    const float* __restrict__ support, const float* __restrict__ epsp,
    u16* __restrict__ Mall, u16* __restrict__ MT)
{
    __shared__ float t[32][33];
    const int tid = threadIdx.x;
    const int s = blockIdx.z, n0 = blockIdx.y * 32, m0 = blockIdx.x * 32;
    const float f = 1.0f + epsp[0];
    const float* S = support + (size_t)s * 262144;
#pragma unroll
    for (int p = 0; p < 4; ++p) {
        int nl = p * 8 + (tid >> 5), ml = tid & 31;
        float v = S[(size_t)(n0 + nl) * 512 + m0 + ml];
        if (n0 + nl == m0 + ml) v += f;
        Mall[(size_t)s * 524288 + (size_t)(n0 + nl) * 512 + m0 + ml] = f2bf(v);
        t[nl][ml] = v;
    }
    __syncthreads();
#pragma unroll
    for (int p = 0; p < 4; ++p) {
        int ml = p * 8 + (tid >> 5), nl = tid & 31;
        MT[(size_t)s * 262144 + (size_t)(m0 + ml) * 512 + n0 + nl] = f2bf(t[nl][ml]);
    }
}

// ---------------------------------------------------------------------------
// Wt[k][o][d] = weight[l][h*4+k][o], d = l*64+h  (bf16, d-contig rows). grid 768.
// ---------------------------------------------------------------------------
__global__ __launch_bounds__(256) void build_Wt(
    const float* __restrict__ w, u16* __restrict__ Wt)
{
    int idx = blockIdx.x * 256 + threadIdx.x;      // 4*64*768 = 196608
    int k = idx / 49152, rem = idx % 49152;
    int o = rem / 768, d = rem % 768;
    int l = d >> 6, hh = d & 63;
    Wt[idx] = f2bf(w[((size_t)l * 256 + hh * 4 + k) * 64 + o]);
}

// ---------------------------------------------------------------------------
// M^2 via MFMA: C[n][m'] = sum_m M[n][m] * MT[m'][m] -> Mall[2s+1] rows.
// 128x128 tile, K=512, BK=32. grid (4,4,2), block 256.
// ---------------------------------------------------------------------------
__global__ __launch_bounds__(256) void msq(
    const u16* __restrict__ Mall_in, const u16* __restrict__ MT,
    u16* __restrict__ Mall_out)
{
    __shared__ __align__(16) u16 sm[8192];
    u16* Ps = sm; u16* Qs = sm + 4096;
    const int tid = threadIdx.x, lane = tid & 63, wid = tid >> 6;
    const int wr = wid >> 1, wc = wid & 1;
    const int s = blockIdx.z, i0 = blockIdx.y * 128, j0 = blockIdx.x * 128;
    const u16* A = Mall_in + (size_t)s * 524288;
    const u16* Bq = MT + (size_t)s * 262144;
    const int lrow = lane & 15, lk = (lane >> 4) * 8;

    const u16* gsrc[4]; u16* ldst[4];
#pragma unroll
    for (int t = 0; t < 4; ++t) {
        int idx = wid * 4 + t;
        if (idx < 8) { gsrc[t] = A  + (size_t)(i0 + idx * 16 + lrow) * 512 + lk; ldst[t] = Ps + idx * 512; }
        else { int s2 = idx - 8; gsrc[t] = Bq + (size_t)(j0 + s2 * 16 + lrow) * 512 + lk; ldst[t] = Qs + s2 * 512; }
    }
    f32x4 acc[4][4] = {};
    for (int k0 = 0; k0 < 512; k0 += 32) {
#pragma unroll
        for (int t = 0; t < 4; ++t) gl2lds16(gsrc[t], ldst[t]);
#pragma unroll
        for (int t = 0; t < 4; ++t) gsrc[t] += 32;
        __syncthreads();
        u16x8 af[4], bq[4];
#pragma unroll
        for (int f = 0; f < 4; ++f) af[f] = *(const u16x8*)(Ps + (wr * 4 + f) * 512 + lane * 8);
#pragma unroll
        for (int f = 0; f < 4; ++f) bq[f] = *(const u16x8*)(Qs + (wc * 4 + f) * 512 + lane * 8);
#pragma unroll
        for (int fi = 0; fi < 4; ++fi)
#pragma unroll
            for (int fj = 0; fj < 4; ++fj) acc[fi][fj] = mfma16(af[fi], bq[fj], acc[fi][fj]);
        __syncthreads();
    }
    const int q = lane >> 4;
    u16* Co = Mall_out + (size_t)s * 524288 + 262144;
#pragma unroll
    for (int fi = 0; fi < 4; ++fi)
#pragma unroll
        for (int fj = 0; fj < 4; ++fj)
#pragma unroll
            for (int r = 0; r < 4; ++r) {
                int n = i0 + wr * 64 + fi * 16 + q * 4 + r;
                int c = j0 + wc * 64 + fj * 16 + lrow;
                Co[(size_t)n * 512 + c] = f2bf(acc[fi][fj][r]);
            }
}

// ---------------------------------------------------------------------------
// Z-GEMM: C[i=(k*64+o)][j=(b*512+m)] = sum_d Wt[i][d] * xb[j][d]
// -> Z[k][b][o][m] bf16.  128x128 tile, K=768, BK=32. grid (128,2), block 256.
// ---------------------------------------------------------------------------
__global__ __launch_bounds__(256) void zgemm(
    const u16* __restrict__ Wt, const u16* __restrict__ xb, u16* __restrict__ Z)
{
    __shared__ __align__(16) char smem[4 * 9216];   // 16KB staging / 36KB repack overlay
    u16* Ps = (u16*)smem;
    u16* Qs = (u16*)(smem + 8192);
    const int tid = threadIdx.x, lane = tid & 63, wid = tid >> 6;
    const int wr = wid >> 1, wc = wid & 1;
    const int j0 = blockIdx.x * 128, i0 = blockIdx.y * 128;
    const int lrow = lane & 15, lk = (lane >> 4) * 8;

    const u16* gsrc[4]; u16* ldst[4];
#pragma unroll
    for (int t = 0; t < 4; ++t) {
        int idx = wid * 4 + t;
        if (idx < 8) { gsrc[t] = Wt + (size_t)(i0 + idx * 16 + lrow) * 768 + lk; ldst[t] = Ps + idx * 512; }
        else { int s2 = idx - 8; gsrc[t] = xb + (size_t)(j0 + s2 * 16 + lrow) * 768 + lk; ldst[t] = Qs + s2 * 512; }
    }
    f32x4 acc[4][4] = {};
    for (int k0 = 0; k0 < 768; k0 += 32) {
#pragma unroll
        for (int t = 0; t < 4; ++t) gl2lds16(gsrc[t], ldst[t]);
#pragma unroll
        for (int t = 0; t < 4; ++t) gsrc[t] += 32;
        __syncthreads();
        u16x8 af[4], bq[4];
#pragma unroll
        for (int f = 0; f < 4; ++f) af[f] = *(const u16x8*)(Ps + (wr * 4 + f) * 512 + lane * 8);
#pragma unroll
        for (int f = 0; f < 4; ++f) bq[f] = *(const u16x8*)(Qs + (wc * 4 + f) * 512 + lane * 8);
#pragma unroll
        for (int fi = 0; fi < 4; ++fi)
#pragma unroll
            for (int fj = 0; fj < 4; ++fj) acc[fi][fj] = mfma16(af[fi], bq[fj], acc[fi][fj]);
        __syncthreads();
    }
    // repack 64x64 per wave in LDS (stride 72 u16), then vectorized store
    u16* Rw = (u16*)(smem + wid * 9216);
    const int q = lane >> 4;
#pragma unroll
    for (int fi = 0; fi < 4; ++fi)
#pragma unroll
        for (int fj = 0; fj < 4; ++fj)
#pragma unroll
            for (int r = 0; r < 4; ++r)
                Rw[(fi * 16 + q * 4 + r) * 72 + fj * 16 + lrow] = f2bf(acc[fi][fj][r]);
    __syncthreads();
    const int kq = blockIdx.y * 2 + wr;            // k index 0..3
    const int b  = j0 >> 9;
    const int m0 = (j0 & 511) + wc * 64;
#pragma unroll
    for (int p = 0; p < 8; ++p) {
        int row = p * 8 + (lane >> 3);             // = o
        int cc  = (lane & 7) * 8;
        u16x8 v = *(const u16x8*)(Rw + row * 72 + cc);
        *(u16x8*)(Z + ((size_t)(kq * 32 + b) * 64 + row) * 512 + m0 + cc) = v;
    }
}

// ---------------------------------------------------------------------------
// Y-GEMM: Y1[k][b][n][o] = sum_m Mall[k][n][m] * Z[k][b][o][m]   (fp32 out)
// block tile 256n x 64o, 4 waves stacked in n, K=512, BK=32.
// grid (2, 128): x=n-tile, y=kb. block 256.
// ---------------------------------------------------------------------------
__global__ __launch_bounds__(256) void ygemm(
    const u16* __restrict__ Mall, const u16* __restrict__ Z, float* __restrict__ Y1)
{
    __shared__ __align__(16) u16 sm[10240];        // A 16 subtiles + B 4 subtiles
    u16* As_ = sm; u16* Bs_ = sm + 8192;
    const int tid = threadIdx.x, lane = tid & 63, wid = tid >> 6;
    const int n0 = blockIdx.x * 256, kb = blockIdx.y;
    const int k = kb >> 5;
    const u16* Ak  = Mall + (size_t)k * 262144;
    const u16* Zkb = Z + (size_t)kb * 64 * 512;
    const int lrow = lane & 15, lk = (lane >> 4) * 8;

    const u16* gsrc[5]; u16* ldst[5];
#pragma unroll
    for (int t = 0; t < 5; ++t) {
        int idx = wid * 5 + t;
        if (idx < 16) { gsrc[t] = Ak + (size_t)(n0 + idx * 16 + lrow) * 512 + lk; ldst[t] = As_ + idx * 512; }
        else { int s2 = idx - 16; gsrc[t] = Zkb + (size_t)(s2 * 16 + lrow) * 512 + lk; ldst[t] = Bs_ + s2 * 512; }
    }
    f32x4 acc[4][4] = {};
    for (int k0 = 0; k0 < 512; k0 += 32) {
#pragma unroll
        for (int t = 0; t < 5; ++t) gl2lds16(gsrc[t], ldst[t]);
#pragma unroll
        for (int t = 0; t < 5; ++t) gsrc[t] += 32;
        __syncthreads();
        u16x8 af[4], bq[4];
#pragma unroll
        for (int f = 0; f < 4; ++f) af[f] = *(const u16x8*)(As_ + (wid * 4 + f) * 512 + lane * 8);
#pragma unroll
        for (int f = 0; f < 4; ++f) bq[f] = *(const u16x8*)(Bs_ + f * 512 + lane * 8);
#pragma unroll
        for (int fi = 0; fi < 4; ++fi)
#pragma unroll
            for (int fj = 0; fj < 4; ++fj) acc[fi][fj] = mfma16(af[fi], bq[fj], acc[fi][fj]);
        __syncthreads();
    }
    const int q = lane >> 4;
    float* Yb = Y1 + (size_t)kb * 512 * 64;
#pragma unroll
    for (int fi = 0; fi < 4; ++fi)
#pragma unroll
        for (int fj = 0; fj < 4; ++fj)
#pragma unroll
            for (int r = 0; r < 4; ++r) {
                int n = n0 + wid * 64 + fi * 16 + q * 4 + r;
                int o = fj * 16 + lrow;
                Yb[(size_t)n * 64 + o] = acc[fi][fj][r];
            }
}

// ---------------------------------------------------------------------------
// BN partials: grid 256, block j handles rows j*64..j*64+63 (r = b*512+n).
// v(r,o) = sum_k Y1[(k<<14)+r][o]. part[j*128+o]=sum, +64 = sumsq.
// ---------------------------------------------------------------------------
__global__ __launch_bounds__(256) void bn_part(
    const float* __restrict__ Y1, float* __restrict__ part)
{
    const int blk = blockIdx.x, tid = threadIdx.x;
    const int o = tid & 63, g = tid >> 6;
    float s = 0.f, s2 = 0.f;
    for (int r = blk * 64 + g; r < blk * 64 + 64; r += 4) {
        float v = 0.f;
#pragma unroll
        for (int k = 0; k < 4; ++k) v += Y1[((size_t)(k << 14) + r) * 64 + o];
        s += v; s2 += v * v;
    }
    __shared__ float ls[4][64], ls2[4][64];
    ls[g][o] = s; ls2[g][o] = s2;
    __syncthreads();
    if (tid < 64) {
        float t = 0.f, t2 = 0.f;
#pragma unroll
        for (int g2 = 0; g2 < 4; ++g2) { t += ls[g2][tid]; t2 += ls2[g2][tid]; }
        part[blk * 128 + tid]      = t;
        part[blk * 128 + 64 + tid] = t2;
    }
}

__global__ __launch_bounds__(256) void bn_final(
    const float* __restrict__ part, float* __restrict__ stats)
{
    const int tid = threadIdx.x;
    const int c = tid & 63, g = tid >> 6;
    float s = 0.f, s2 = 0.f;
    for (int b = g; b < 256; b += 4) {
        s  += part[b * 128 + c];
        s2 += part[b * 128 + 64 + c];
    }
    __shared__ float ls[4][64], ls2[4][64];
    ls[g][c] = s; ls2[g][c] = s2;
    __syncthreads();
    if (tid < 64) {
        float t = 0.f, t2 = 0.f;
#pragma unroll
        for (int g2 = 0; g2 < 4; ++g2) { t += ls[g2][tid]; t2 += ls2[g2][tid]; }
        float mean = t * (1.0f / R_);
        float var  = t2 * (1.0f / R_) - mean * mean;
        stats[tid]      = mean;
        stats[64 + tid] = rsqrtf(var + 1e-5f);
    }
}

// ---------------------------------------------------------------------------
// Fused BN + ReLU + w2 GEMM + b2. grid 256 (64 rows each), block 256.
// ---------------------------------------------------------------------------
__global__ __launch_bounds__(256) void bn_out(
    const float* __restrict__ Y1, const float* __restrict__ stats,
    const float* __restrict__ gamma, const float* __restrict__ beta,
    const float* __restrict__ w2, const float* __restrict__ b2,
    float* __restrict__ out)
{
    __shared__ float ys[64 * 68];    // [c][rl], stride 68 (16B-aligned rows)
    __shared__ float w2s[64 * 65];
    __shared__ float mn[64], rs[64], ga[64], be[64], bb[64];
    const int tid = threadIdx.x;
    const int r0 = blockIdx.x * 64;
#pragma unroll
    for (int i = 0; i < 16; ++i) {
        int idx = tid + i * 256;
        w2s[(idx >> 6) * 65 + (idx & 63)] = w2[idx];
    }
    if (tid < 64) {
        mn[tid] = stats[tid]; rs[tid] = stats[64 + tid];
        ga[tid] = gamma[tid]; be[tid] = beta[tid]; bb[tid] = b2[tid];
    }
    __syncthreads();
    const int o = tid & 63, rg = tid >> 6;
#pragma unroll
    for (int p = 0; p < 16; ++p) {
        int rl = p * 4 + rg;
        int r = r0 + rl;
        float v = 0.f;
#pragma unroll
        for (int k = 0; k < 4; ++k) v += Y1[((size_t)(k << 14) + r) * 64 + o];
        v = (v - mn[o]) * rs[o] * ga[o] + be[o];
        ys[o * 68 + rl] = fmaxf(v, 0.f);
    }
    __syncthreads();
    const int ol = tid & 63, rg2 = tid >> 6;
    float acc[16];
#pragma unroll
    for (int j = 0; j < 16; ++j) acc[j] = bb[ol];
    for (int c = 0; c < 64; ++c) {
        float wv = w2s[ol * 65 + c];
        const float* yr = ys + c * 68 + rg2 * 16;
        f32x4 y0 = *(const f32x4*)(yr);
        f32x4 y1 = *(const f32x4*)(yr + 4);
        f32x4 y2 = *(const f32x4*)(yr + 8);
        f32x4 y3 = *(const f32x4*)(yr + 12);
#pragma unroll
        for (int j = 0; j < 4; ++j) {
            acc[j]      = fmaf(wv, y0[j], acc[j]);
            acc[4 + j]  = fmaf(wv, y1[j], acc[4 + j]);
            acc[8 + j]  = fmaf(wv, y2[j], acc[8 + j]);
            acc[12 + j] = fmaf(wv, y3[j], acc[12 + j]);
        }
    }
#pragma unroll
    for (int j = 0; j < 16; ++j)
        out[(size_t)(r0 + rg2 * 16 + j) * OUT_ + ol] = acc[j];
}

// ---------------------------------------------------------------------------
extern "C" void kernel_launch(void* const* d_in, const int* in_sizes, int n_in,
                              void* d_out, int out_size, void* d_ws, size_t ws_size,
                              hipStream_t stream)
{
    const float* x       = (const float*)d_in[0];
    const float* support = (const float*)d_in[1];
    const float* weight  = (const float*)d_in[2];
    const float* eps     = (const float*)d_in[3];
    const float* gamma   = (const float*)d_in[4];
    const float* beta    = (const float*)d_in[5];
    const float* w2      = (const float*)d_in[6];
    const float* b2      = (const float*)d_in[7];
    float* out = (float*)d_out;

    char* ws = (char*)d_ws;
    u16*   xb    = (u16*)(ws);                      // 25,165,824
    u16*   Mall  = (u16*)(ws + 25165824);           //  2,097,152
    u16*   MT    = (u16*)(ws + 27262976);           //  1,048,576
    u16*   Wt    = (u16*)(ws + 28311552);           //    393,216
    u16*   Z     = (u16*)(ws + 28704768);           //  8,388,608
    float* Y1    = (float*)(ws + 37093376);         // 16,777,216
    float* part  = (float*)(ws + 53870592);         //    131,072
    float* stats = (float*)(ws + 54001664);         //        512

    cast_x  <<<6144,            256, 0, stream>>>(x, xb);
    build_M <<<dim3(16, 16, 2), 256, 0, stream>>>(support, eps, Mall, MT);
    build_Wt<<<768,             256, 0, stream>>>(weight, Wt);
    msq     <<<dim3(4, 4, 2),   256, 0, stream>>>(Mall, MT, Mall);
    zgemm   <<<dim3(128, 2),    256, 0, stream>>>(Wt, xb, Z);
    ygemm   <<<dim3(2, 128),    256, 0, stream>>>(Mall, Z, Y1);
    bn_part <<<256,             256, 0, stream>>>(Y1, part);
    bn_final<<<1,               256, 0, stream>>>(part, stats);
    bn_out  <<<256,             256, 0, stream>>>(Y1, stats, gamma, beta, w2, b2, out);
}